// Round 5
// baseline (149.407 us; speedup 1.0000x reference)
//
#include <hip/hip_runtime.h>

// Accumulate in log2 space; clamp = -100/ln(2); scale by ln(2) once at the end.
#define LOG2_CLAMP -144.269504088896f
#define LN2 0.69314718055994530942
#define GRID 2048
#define BLOCK 256

// Stage 1: per-block partials, no atomics.
// ws layout (float): part_total[GRID] | part_s1[GRID] | part_cnt[GRID]
//   total = sum over ALL elements of -max(log2(t), clamp), t = gt ? x : 1-x
//   s1    = same sum restricted to gt==1;  S0 = total - S1
// Stage 2: one block reduces partials in double, applies ln2, writes scalar.

__device__ __forceinline__ float log2_clamped(float v) {
  return fmaxf(__builtin_amdgcn_logf(v), LOG2_CLAMP);
}

#define ACC1(xe, ge)                              \
  {                                               \
    float t = (ge) ? (xe) : 1.0f - (xe);          \
    float l = log2_clamped(t);                    \
    tot -= l;                                     \
    s1 -= (ge) ? l : 0.0f;                        \
    icnt += (ge) ? 1 : 0;                         \
  }

#define ACC4(xv, gv)                              \
  ACC1(xv.x, gv.x) ACC1(xv.y, gv.y)               \
  ACC1(xv.z, gv.z) ACC1(xv.w, gv.w)

__global__ __launch_bounds__(BLOCK) void bce_stage1(
    const float* __restrict__ x, const int* __restrict__ gt,
    int n, float* __restrict__ part) {
  float tot = 0.0f, s1 = 0.0f;
  int icnt = 0;

  const int tid = blockIdx.x * BLOCK + threadIdx.x;
  const int stride = GRID * BLOCK;
  const int n4 = n >> 2;
  const float4* __restrict__ x4 = reinterpret_cast<const float4*>(x);
  const int4* __restrict__ g4 = reinterpret_cast<const int4*>(gt);

  int i = tid;
  // 8-deep: issue all 16 independent 16B loads before any use (max MLP,
  // single latency exposure per thread at n = 16.7M).
  for (; i + 7 * stride < n4; i += 8 * stride) {
    float4 xa = x4[i];
    float4 xb = x4[i + stride];
    float4 xc = x4[i + 2 * stride];
    float4 xd = x4[i + 3 * stride];
    float4 xe = x4[i + 4 * stride];
    float4 xf = x4[i + 5 * stride];
    float4 xg = x4[i + 6 * stride];
    float4 xh = x4[i + 7 * stride];
    int4 ga = g4[i];
    int4 gb = g4[i + stride];
    int4 gc = g4[i + 2 * stride];
    int4 gd = g4[i + 3 * stride];
    int4 ge = g4[i + 4 * stride];
    int4 gf = g4[i + 5 * stride];
    int4 gg = g4[i + 6 * stride];
    int4 gh = g4[i + 7 * stride];
    ACC4(xa, ga) ACC4(xb, gb) ACC4(xc, gc) ACC4(xd, gd)
    ACC4(xe, ge) ACC4(xf, gf) ACC4(xg, gg) ACC4(xh, gh)
  }
  for (; i < n4; i += stride) {
    float4 xa = x4[i];
    int4 ga = g4[i];
    ACC4(xa, ga)
  }
  for (int j = (n4 << 2) + tid; j < n; j += stride) {
    float xv = x[j];
    int gv = gt[j];
    ACC1(xv, gv)
  }

  float cnt = (float)icnt;  // <= 8192 per block: exact in float

  // wave-level reduction (64 lanes)
  for (int off = 32; off > 0; off >>= 1) {
    tot += __shfl_down(tot, off, 64);
    s1  += __shfl_down(s1, off, 64);
    cnt += __shfl_down(cnt, off, 64);
  }

  __shared__ float red[3][BLOCK / 64];
  const int lane = threadIdx.x & 63;
  const int wave = threadIdx.x >> 6;
  if (lane == 0) {
    red[0][wave] = tot;
    red[1][wave] = s1;
    red[2][wave] = cnt;
  }
  __syncthreads();
  if (threadIdx.x == 0) {
    part[blockIdx.x]            = red[0][0] + red[0][1] + red[0][2] + red[0][3];
    part[GRID + blockIdx.x]     = red[1][0] + red[1][1] + red[1][2] + red[1][3];
    part[2 * GRID + blockIdx.x] = red[2][0] + red[2][1] + red[2][2] + red[2][3];
  }
}

__global__ __launch_bounds__(BLOCK) void bce_stage2(
    const float* __restrict__ part, float* __restrict__ out, double n) {
  double tot = 0.0, s1 = 0.0, cnt = 0.0;
  for (int i = threadIdx.x; i < GRID; i += BLOCK) {
    tot += (double)part[i];
    s1  += (double)part[GRID + i];
    cnt += (double)part[2 * GRID + i];
  }
  for (int off = 32; off > 0; off >>= 1) {
    tot += __shfl_down(tot, off, 64);
    s1  += __shfl_down(s1, off, 64);
    cnt += __shfl_down(cnt, off, 64);
  }
  __shared__ double red[3][BLOCK / 64];
  const int lane = threadIdx.x & 63;
  const int wave = threadIdx.x >> 6;
  if (lane == 0) {
    red[0][wave] = tot;
    red[1][wave] = s1;
    red[2][wave] = cnt;
  }
  __syncthreads();
  if (threadIdx.x == 0) {
    double T = (red[0][0] + red[0][1] + red[0][2] + red[0][3]) * LN2;
    double S1 = (red[1][0] + red[1][1] + red[1][2] + red[1][3]) * LN2;
    double s = red[2][0] + red[2][1] + red[2][2] + red[2][3];
    double S0 = T - S1;
    // result = S1/(2s) + S0/(2(n-s))
    out[0] = (float)(S1 / (2.0 * s) + S0 / (2.0 * (n - s)));
  }
}

extern "C" void kernel_launch(void* const* d_in, const int* in_sizes, int n_in,
                              void* d_out, int out_size, void* d_ws, size_t ws_size,
                              hipStream_t stream) {
  const float* x = (const float*)d_in[0];
  const int* gt = (const int*)d_in[1];
  float* out = (float*)d_out;
  int n = in_sizes[0];

  float* part = (float*)d_ws;  // 3*GRID floats; every slot written each launch

  bce_stage1<<<GRID, BLOCK, 0, stream>>>(x, gt, n, part);
  bce_stage2<<<1, BLOCK, 0, stream>>>(part, out, (double)n);
}

// Round 7
// 140.472 us; speedup vs baseline: 1.0636x; 1.0636x over previous
//
#include <hip/hip_runtime.h>

// Accumulate in log2 space; clamp = -100/ln(2); scale by ln(2) once at the end.
#define LOG2_CLAMP -144.269504088896f
#define LN2 0.69314718055994530942
#define GRID 2048
#define BLOCK 256

// clang ext_vector types: __builtin_nontemporal_load requires these
// (HIP_vector_type float4/int4 are rejected). Same codegen: global_load_dwordx4.
typedef float fx4 __attribute__((ext_vector_type(4)));
typedef int ix4 __attribute__((ext_vector_type(4)));

// Stage 1: block-contiguous chunks (DRAM-sequential per block), depth-2
// software pipeline (4 loads in flight/thread), non-temporal loads.
// Per-block partials, no atomics.
// ws layout (float): part_total[GRID] | part_s1[GRID] | part_cnt[GRID]
//   total = sum over ALL elements of -max(log2(t), clamp), t = gt ? x : 1-x
//   s1    = same sum restricted to gt==1;  S0 = total - S1
// Stage 2: one block reduces partials in double, applies ln2, writes scalar.

__device__ __forceinline__ float log2_clamped(float v) {
  return fmaxf(__builtin_amdgcn_logf(v), LOG2_CLAMP);
}

#define ACC1(xe, ge)                              \
  {                                               \
    float t = (ge) ? (xe) : 1.0f - (xe);          \
    float l = log2_clamped(t);                    \
    tot -= l;                                     \
    s1 -= (ge) ? l : 0.0f;                        \
    icnt += (ge) ? 1 : 0;                         \
  }

#define ACC4(xv, gv)                              \
  ACC1(xv.x, gv.x) ACC1(xv.y, gv.y)               \
  ACC1(xv.z, gv.z) ACC1(xv.w, gv.w)

__global__ __launch_bounds__(BLOCK) void bce_stage1(
    const float* __restrict__ x, const int* __restrict__ gt,
    int n, float* __restrict__ part) {
  float tot = 0.0f, s1 = 0.0f;
  int icnt = 0;

  const int n4 = n >> 2;
  const int chunk = (n4 + GRID - 1) / GRID;           // float4s per block
  const int start = blockIdx.x * chunk;
  const int end = min(start + chunk, n4);
  const fx4* __restrict__ x4 = reinterpret_cast<const fx4*>(x);
  const ix4* __restrict__ g4 = reinterpret_cast<const ix4*>(gt);

  // Depth-2 software pipeline over the block's contiguous chunk.
  int i = start + (int)threadIdx.x;
  fx4 xcur = {0.5f, 0.5f, 0.5f, 0.5f}, xnext = {0.5f, 0.5f, 0.5f, 0.5f};
  ix4 gcur = {0, 0, 0, 0}, gnext = {0, 0, 0, 0};
  if (i < end) {
    xcur = __builtin_nontemporal_load(&x4[i]);
    gcur = __builtin_nontemporal_load(&g4[i]);
  }
  if (i + BLOCK < end) {
    xnext = __builtin_nontemporal_load(&x4[i + BLOCK]);
    gnext = __builtin_nontemporal_load(&g4[i + BLOCK]);
  }
  for (; i < end; i += BLOCK) {
    fx4 xc = xcur;
    ix4 gc = gcur;
    xcur = xnext;
    gcur = gnext;
    const int ip2 = i + 2 * BLOCK;
    if (ip2 < end) {
      xnext = __builtin_nontemporal_load(&x4[ip2]);
      gnext = __builtin_nontemporal_load(&g4[ip2]);
    }
    ACC4(xc, gc)
  }

  // scalar tail (n not divisible by 4), spread over the whole grid
  for (int j = (n4 << 2) + blockIdx.x * BLOCK + (int)threadIdx.x; j < n;
       j += GRID * BLOCK) {
    float xv = x[j];
    int gv = gt[j];
    ACC1(xv, gv)
  }

  float cnt = (float)icnt;  // small per thread: exact in float

  // wave-level reduction (64 lanes)
  for (int off = 32; off > 0; off >>= 1) {
    tot += __shfl_down(tot, off, 64);
    s1  += __shfl_down(s1, off, 64);
    cnt += __shfl_down(cnt, off, 64);
  }

  __shared__ float red[3][BLOCK / 64];
  const int lane = threadIdx.x & 63;
  const int wave = threadIdx.x >> 6;
  if (lane == 0) {
    red[0][wave] = tot;
    red[1][wave] = s1;
    red[2][wave] = cnt;
  }
  __syncthreads();
  if (threadIdx.x == 0) {
    part[blockIdx.x]            = red[0][0] + red[0][1] + red[0][2] + red[0][3];
    part[GRID + blockIdx.x]     = red[1][0] + red[1][1] + red[1][2] + red[1][3];
    part[2 * GRID + blockIdx.x] = red[2][0] + red[2][1] + red[2][2] + red[2][3];
  }
}

__global__ __launch_bounds__(BLOCK) void bce_stage2(
    const float* __restrict__ part, float* __restrict__ out, double n) {
  double tot = 0.0, s1 = 0.0, cnt = 0.0;
  for (int i = threadIdx.x; i < GRID; i += BLOCK) {
    tot += (double)part[i];
    s1  += (double)part[GRID + i];
    cnt += (double)part[2 * GRID + i];
  }
  for (int off = 32; off > 0; off >>= 1) {
    tot += __shfl_down(tot, off, 64);
    s1  += __shfl_down(s1, off, 64);
    cnt += __shfl_down(cnt, off, 64);
  }
  __shared__ double red[3][BLOCK / 64];
  const int lane = threadIdx.x & 63;
  const int wave = threadIdx.x >> 6;
  if (lane == 0) {
    red[0][wave] = tot;
    red[1][wave] = s1;
    red[2][wave] = cnt;
  }
  __syncthreads();
  if (threadIdx.x == 0) {
    double T  = (red[0][0] + red[0][1] + red[0][2] + red[0][3]) * LN2;
    double S1 = (red[1][0] + red[1][1] + red[1][2] + red[1][3]) * LN2;
    double s  = red[2][0] + red[2][1] + red[2][2] + red[2][3];
    double S0 = T - S1;
    // result = S1/(2s) + S0/(2(n-s))
    out[0] = (float)(S1 / (2.0 * s) + S0 / (2.0 * (n - s)));
  }
}

extern "C" void kernel_launch(void* const* d_in, const int* in_sizes, int n_in,
                              void* d_out, int out_size, void* d_ws, size_t ws_size,
                              hipStream_t stream) {
  const float* x = (const float*)d_in[0];
  const int* gt = (const int*)d_in[1];
  float* out = (float*)d_out;
  int n = in_sizes[0];

  float* part = (float*)d_ws;  // 3*GRID floats; every slot written each launch

  bce_stage1<<<GRID, BLOCK, 0, stream>>>(x, gt, n, part);
  bce_stage2<<<1, BLOCK, 0, stream>>>(part, out, (double)n);
}

// Round 8
// 138.460 us; speedup vs baseline: 1.0791x; 1.0145x over previous
//
#include <hip/hip_runtime.h>

// Accumulate in log2 space; clamp = -100/ln(2); scale by ln(2) once at the end.
#define LOG2_CLAMP -144.269504088896f
#define LN2 0.69314718055994530942
#define GRID 2048
#define BLOCK 256

// clang ext_vector types: __builtin_nontemporal_load requires these
// (HIP_vector_type float4/int4 are rejected). Same codegen: global_load_dwordx4.
typedef float fx4 __attribute__((ext_vector_type(4)));
typedef int ix4 __attribute__((ext_vector_type(4)));

// ws layout (float): part_total[GRID] | part_s1[GRID] | part_cnt[GRID]
//   total = sum over ALL elements of -max(log2(t), clamp), t = gt ? x : 1-x
//   s1    = same sum restricted to gt==1;  S0 = total - S1

__device__ __forceinline__ float log2_clamped(float v) {
  return fmaxf(__builtin_amdgcn_logf(v), LOG2_CLAMP);
}

#define ACC1(xe, ge)                              \
  {                                               \
    float t = (ge) ? (xe) : 1.0f - (xe);          \
    float l = log2_clamped(t);                    \
    tot -= l;                                     \
    s1 -= (ge) ? l : 0.0f;                        \
    icnt += (ge) ? 1 : 0;                         \
  }

#define ACC4(xv, gv)                              \
  ACC1(xv.x, gv.x) ACC1(xv.y, gv.y)               \
  ACC1(xv.z, gv.z) ACC1(xv.w, gv.w)

__device__ __forceinline__ void block_reduce_store(
    float tot, float s1, float cnt, float* __restrict__ part) {
  for (int off = 32; off > 0; off >>= 1) {
    tot += __shfl_down(tot, off, 64);
    s1  += __shfl_down(s1, off, 64);
    cnt += __shfl_down(cnt, off, 64);
  }
  __shared__ float red[3][BLOCK / 64];
  const int lane = threadIdx.x & 63;
  const int wave = threadIdx.x >> 6;
  if (lane == 0) {
    red[0][wave] = tot;
    red[1][wave] = s1;
    red[2][wave] = cnt;
  }
  __syncthreads();
  if (threadIdx.x == 0) {
    part[blockIdx.x]            = red[0][0] + red[0][1] + red[0][2] + red[0][3];
    part[GRID + blockIdx.x]     = red[1][0] + red[1][1] + red[1][2] + red[1][3];
    part[2 * GRID + blockIdx.x] = red[2][0] + red[2][1] + red[2][2] + red[2][3];
  }
}

// Fast path: n == GRID*BLOCK*4*ITERS exactly. Each thread owns ITERS
// float4+int4 pairs inside its block's contiguous chunk. Zero branches,
// compile-time trip counts, all loads issuable before any use; the block's
// instantaneous footprint stays local (ITERS*BLOCK*16B*2 = 64 KB).
template <int ITERS>
__global__ __launch_bounds__(BLOCK) void bce_stage1_fast(
    const float* __restrict__ x, const int* __restrict__ gt,
    float* __restrict__ part) {
  const fx4* __restrict__ x4 = reinterpret_cast<const fx4*>(x);
  const ix4* __restrict__ g4 = reinterpret_cast<const ix4*>(gt);
  const int base = blockIdx.x * (ITERS * BLOCK) + (int)threadIdx.x;

  fx4 xv[ITERS];
  ix4 gv[ITERS];
#pragma unroll
  for (int k = 0; k < ITERS; ++k)
    xv[k] = __builtin_nontemporal_load(&x4[base + k * BLOCK]);
#pragma unroll
  for (int k = 0; k < ITERS; ++k)
    gv[k] = __builtin_nontemporal_load(&g4[base + k * BLOCK]);

  float tot = 0.0f, s1 = 0.0f;
  int icnt = 0;
#pragma unroll
  for (int k = 0; k < ITERS; ++k) {
    ACC4(xv[k], gv[k])
  }

  block_reduce_store(tot, s1, (float)icnt, part);
}

// Generic fallback (any n): block-contiguous chunks, depth-2 pipeline.
__global__ __launch_bounds__(BLOCK) void bce_stage1(
    const float* __restrict__ x, const int* __restrict__ gt,
    int n, float* __restrict__ part) {
  float tot = 0.0f, s1 = 0.0f;
  int icnt = 0;

  const int n4 = n >> 2;
  const int chunk = (n4 + GRID - 1) / GRID;
  const int start = blockIdx.x * chunk;
  const int end = min(start + chunk, n4);
  const fx4* __restrict__ x4 = reinterpret_cast<const fx4*>(x);
  const ix4* __restrict__ g4 = reinterpret_cast<const ix4*>(gt);

  int i = start + (int)threadIdx.x;
  fx4 xcur = {0.5f, 0.5f, 0.5f, 0.5f}, xnext = {0.5f, 0.5f, 0.5f, 0.5f};
  ix4 gcur = {0, 0, 0, 0}, gnext = {0, 0, 0, 0};
  if (i < end) {
    xcur = __builtin_nontemporal_load(&x4[i]);
    gcur = __builtin_nontemporal_load(&g4[i]);
  }
  if (i + BLOCK < end) {
    xnext = __builtin_nontemporal_load(&x4[i + BLOCK]);
    gnext = __builtin_nontemporal_load(&g4[i + BLOCK]);
  }
  for (; i < end; i += BLOCK) {
    fx4 xc = xcur;
    ix4 gc = gcur;
    xcur = xnext;
    gcur = gnext;
    const int ip2 = i + 2 * BLOCK;
    if (ip2 < end) {
      xnext = __builtin_nontemporal_load(&x4[ip2]);
      gnext = __builtin_nontemporal_load(&g4[ip2]);
    }
    ACC4(xc, gc)
  }

  for (int j = (n4 << 2) + blockIdx.x * BLOCK + (int)threadIdx.x; j < n;
       j += GRID * BLOCK) {
    float xv = x[j];
    int gv = gt[j];
    ACC1(xv, gv)
  }

  block_reduce_store(tot, s1, (float)icnt, part);
}

__global__ __launch_bounds__(BLOCK) void bce_stage2(
    const float* __restrict__ part, float* __restrict__ out, double n) {
  double tot = 0.0, s1 = 0.0, cnt = 0.0;
  for (int i = threadIdx.x; i < GRID; i += BLOCK) {
    tot += (double)part[i];
    s1  += (double)part[GRID + i];
    cnt += (double)part[2 * GRID + i];
  }
  for (int off = 32; off > 0; off >>= 1) {
    tot += __shfl_down(tot, off, 64);
    s1  += __shfl_down(s1, off, 64);
    cnt += __shfl_down(cnt, off, 64);
  }
  __shared__ double red[3][BLOCK / 64];
  const int lane = threadIdx.x & 63;
  const int wave = threadIdx.x >> 6;
  if (lane == 0) {
    red[0][wave] = tot;
    red[1][wave] = s1;
    red[2][wave] = cnt;
  }
  __syncthreads();
  if (threadIdx.x == 0) {
    double T  = (red[0][0] + red[0][1] + red[0][2] + red[0][3]) * LN2;
    double S1 = (red[1][0] + red[1][1] + red[1][2] + red[1][3]) * LN2;
    double s  = red[2][0] + red[2][1] + red[2][2] + red[2][3];
    double S0 = T - S1;
    // result = S1/(2s) + S0/(2(n-s))
    out[0] = (float)(S1 / (2.0 * s) + S0 / (2.0 * (n - s)));
  }
}

extern "C" void kernel_launch(void* const* d_in, const int* in_sizes, int n_in,
                              void* d_out, int out_size, void* d_ws, size_t ws_size,
                              hipStream_t stream) {
  const float* x = (const float*)d_in[0];
  const int* gt = (const int*)d_in[1];
  float* out = (float*)d_out;
  int n = in_sizes[0];

  float* part = (float*)d_ws;  // 3*GRID floats; every slot written each launch

  if (n == GRID * BLOCK * 4 * 8) {
    bce_stage1_fast<8><<<GRID, BLOCK, 0, stream>>>(x, gt, part);
  } else {
    bce_stage1<<<GRID, BLOCK, 0, stream>>>(x, gt, n, part);
  }
  bce_stage2<<<1, BLOCK, 0, stream>>>(part, out, (double)n);
}